// Round 10
// baseline (327.450 us; speedup 1.0000x reference)
//
#include <hip/hip_runtime.h>
#include <cstdio>

// ---------------- problem constants ----------------
constexpr int T  = 4096;       // B*S tokens
constexpr int D  = 1024;       // n_embed
constexpr int M  = 1408;       // n_moe_mlp
constexpr int E  = 8;          // experts

constexpr int TM = 128;        // token-rows per tile
constexpr int TN = 128;        // output cols per tile
constexpr int BK = 32;         // K-step
constexpr int MT_MAX = T / TM; // 32 row-tiles max per expert
constexpr int NT_UP = M / TN;  // 11
constexpr int NT_DN = D / TN;  // 8
constexpr int RCAP = T * 2 + E * TM;  // 9216 padded row capacity (Hid)

constexpr int CSTR = 64;       // per-expert counter stride in ints (256 B)
constexpr int XCV  = T / 2;    // 2048 convert+router blocks (2 tokens each)
constexpr int TPW  = E * (D / 64) * (M / 64);   // 2816 transpose tiles per weight
constexpr int PREP_GRID = XCV + 2 * TPW;        // convert+router, wg/wu transposes
constexpr int NGEMM_UP  = E * MT_MAX * NT_UP;   // 2816
constexpr int UPG_GRID  = NGEMM_UP + TPW;       // + wd transpose blocks (fill slack)

typedef _Float16 half8 __attribute__((ext_vector_type(8)));
typedef float    floatx4 __attribute__((ext_vector_type(4)));

// counted vmcnt waits (T4): never drain to 0 in the main loop.
#define VMW12() asm volatile("s_waitcnt vmcnt(12)" ::: "memory")
#define VMW6()  asm volatile("s_waitcnt vmcnt(6)"  ::: "memory")
#define VMW4()  asm volatile("s_waitcnt vmcnt(4)"  ::: "memory")
#define VMW0()  asm volatile("s_waitcnt vmcnt(0)"  ::: "memory")

// ---------------- ws layout (bytes) ----------------
constexpr size_t OFF_COUNTS = 0;                                // E*CSTR ints (2KB)
constexpr size_t OFF_TLIST  = 2048;                             // E*T ints  (128KB)
constexpr size_t OFF_PLIST  = OFF_TLIST + (size_t)E * T * 4;    // E*T floats(128KB)
constexpr size_t OFF_XH     = OFF_PLIST + (size_t)E * T * 4;    // T x D f16 (8.4MB)
constexpr size_t OFF_HID    = OFF_XH  + (size_t)T * D * 2;      // RCAP x M f16
constexpr size_t OFF_WGT    = OFF_HID + (size_t)RCAP * M * 2;   // E x M x D f16
constexpr size_t OFF_WUT    = OFF_WGT + (size_t)E * M * D * 2;
constexpr size_t OFF_WDT    = OFF_WUT + (size_t)E * M * D * 2;  // E x D x M f16
constexpr size_t WS_NEED    = OFF_WDT + (size_t)E * D * M * 2;

// async global->LDS, 16B per lane. LDS dest = wave-uniform base + lane*16;
// GLOBAL source is per-lane (enables gather + source-side swizzle).
__device__ __forceinline__ void gl_lds16(const void* g, void* l) {
  __builtin_amdgcn_global_load_lds(
      (const __attribute__((address_space(1))) unsigned int*)g,
      (__attribute__((address_space(3))) unsigned int*)l, 16, 0, 0);
}

// 8-expert padded prefix via uniform scalar loads.
__device__ __forceinline__ void expert_base_pc(const int* __restrict__ counts,
                                               int e, int& base_e, int& pc_e,
                                               int& cnt_e) {
  int b = 0; base_e = 0; pc_e = 0; cnt_e = 0;
  #pragma unroll
  for (int ee = 0; ee < E; ++ee) {
    int c = counts[ee * CSTR];
    int p = (c + TM - 1) / TM * TM;
    if (ee == e) { base_e = b; pc_e = p; cnt_e = c; }
    b += p;
  }
}

// ---------------- 64x64 f32->f16 transpose tile (round-8, verified) -----------
__device__ __forceinline__ void transpose64(
    const float* __restrict__ src, _Float16* __restrict__ dst,
    int Rr, int Cc, int j, float (*tile)[69]) {
  int ctn = Cc >> 6, rtn = Rr >> 6;
  int e   = j / (ctn * rtn);
  int rem = j - e * (ctn * rtn);
  int rt = rem / ctn, ct = rem - rt * ctn;
  int t = threadIdx.x;
  int lr = t >> 2;            // 0..63 source row
  int lc = (t & 3) * 16;      // 16-float chunk
  const float* s = src + ((size_t)e * Rr + rt * 64 + lr) * Cc + ct * 64 + lc;
  float4 v0 = *(const float4*)(s + 0);
  float4 v1 = *(const float4*)(s + 4);
  float4 v2 = *(const float4*)(s + 8);
  float4 v3 = *(const float4*)(s + 12);
  float* tr = &tile[lr][lc];
  tr[0]  = v0.x; tr[1]  = v0.y; tr[2]  = v0.z; tr[3]  = v0.w;
  tr[4]  = v1.x; tr[5]  = v1.y; tr[6]  = v1.z; tr[7]  = v1.w;
  tr[8]  = v2.x; tr[9]  = v2.y; tr[10] = v2.z; tr[11] = v2.w;
  tr[12] = v3.x; tr[13] = v3.y; tr[14] = v3.z; tr[15] = v3.w;
  __syncthreads();
  #pragma unroll
  for (int rep = 0; rep < 2; ++rep) {
    int s2 = t + rep * 256;
    int oc = s2 >> 3;         // 0..63 output row (= source col)
    int sl = s2 & 7;          // 16B segment within output row
    half8 o;
    #pragma unroll
    for (int q = 0; q < 8; ++q) o[q] = (_Float16)tile[sl * 8 + q][oc];
    *(half8*)(dst + ((size_t)e * Cc + ct * 64 + oc) * Rr + rt * 64 + sl * 8) = o;
  }
}

// ---------------- fused prep: (x->f16 convert + router) + wg/wu transposes ----
// Convert blocks each own 2 token rows; the router dot is computed from the
// SAME loaded values (removes the 16 MB x re-read + 256 standalone router
// blocks).  Slot maps: tlist (slot->token), plist (slot->prob).
__global__ __launch_bounds__(256) void k_prep(
    const float* __restrict__ x, const float* __restrict__ wgate,
    const float* __restrict__ w_g, const float* __restrict__ w_u,
    _Float16* __restrict__ Xh,
    _Float16* __restrict__ wgT, _Float16* __restrict__ wuT,
    int* __restrict__ counts, int* __restrict__ tlist,
    float* __restrict__ plist) {
  __shared__ float tile[64][69];
  __shared__ float s_red[4][8];
  int bid = blockIdx.x;

  if (bid < XCV) {
    int tid = threadIdx.x;
    int row  = tid >> 7;             // 0 or 1
    int t    = bid * 2 + row;
    int dpos = (tid & 127) * 8;      // 0..1023
    int wv = tid >> 6, lane = tid & 63;
    const float* xr = x + (size_t)t * D + dpos;
    float4 v0 = *(const float4*)(xr);
    float4 v1 = *(const float4*)(xr + 4);
    half8 h;
    h[0] = (_Float16)v0.x; h[1] = (_Float16)v0.y;
    h[2] = (_Float16)v0.z; h[3] = (_Float16)v0.w;
    h[4] = (_Float16)v1.x; h[5] = (_Float16)v1.y;
    h[6] = (_Float16)v1.z; h[7] = (_Float16)v1.w;
    *(half8*)(Xh + (size_t)t * D + dpos) = h;
    // router partials: 8 elems x 8 experts
    float xv[8] = {v0.x, v0.y, v0.z, v0.w, v1.x, v1.y, v1.z, v1.w};
    float acc[8] = {0.f,0.f,0.f,0.f,0.f,0.f,0.f,0.f};
    #pragma unroll
    for (int j = 0; j < 8; ++j) {
      const float4* wr2 = (const float4*)(wgate + (size_t)(dpos + j) * E);
      float4 w0 = wr2[0], w1 = wr2[1];
      acc[0] += xv[j] * w0.x; acc[1] += xv[j] * w0.y;
      acc[2] += xv[j] * w0.z; acc[3] += xv[j] * w0.w;
      acc[4] += xv[j] * w1.x; acc[5] += xv[j] * w1.y;
      acc[6] += xv[j] * w1.z; acc[7] += xv[j] * w1.w;
    }
    #pragma unroll
    for (int e = 0; e < 8; ++e) {
      #pragma unroll
      for (int off = 32; off; off >>= 1) acc[e] += __shfl_xor(acc[e], off, 64);
    }
    if (lane == 0) {
      #pragma unroll
      for (int e = 0; e < 8; ++e) s_red[wv][e] = acc[e];
    }
    __syncthreads();
    if ((tid & 127) == 0) {
      int wb = row * 2;
      float sc[8];
      #pragma unroll
      for (int e = 0; e < 8; ++e) sc[e] = s_red[wb][e] + s_red[wb + 1][e];
      int i0 = 0; float s0 = sc[0];
      #pragma unroll
      for (int e = 1; e < 8; ++e) if (sc[e] > s0) { s0 = sc[e]; i0 = e; }
      int i1 = -1; float s1 = -1e30f;
      #pragma unroll
      for (int e = 0; e < 8; ++e) if (e != i0 && sc[e] > s1) { s1 = sc[e]; i1 = e; }
      float p0 = 1.f / (1.f + expf(s1 - s0));
      float p1 = 1.f - p0;
      int q0 = atomicAdd(&counts[i0 * CSTR], 1);
      int q1 = atomicAdd(&counts[i1 * CSTR], 1);
      tlist[i0 * T + q0] = t; plist[i0 * T + q0] = p0;
      tlist[i1 * T + q1] = t; plist[i1 * T + q1] = p1;
    }
    return;
  }

  // ---- wg / wu transpose-convert ----
  int i = bid - XCV;
  if (i < TPW) transpose64(w_g, wgT, D, M, i, tile);
  else         transpose64(w_u, wuT, D, M, i - TPW, tile);
}

// ---------------- fused gate+up grouped GEMM + SiLU (+ wd transpose blocks) ---
// GEMM body identical to round-8 (verified): 3-buffer counted-vmcnt pipeline,
// gather-A from Xh, both-sides LDS swizzle, wd-transpose piggyback.
__global__ __launch_bounds__(256, 2) void k_upgate(
    const _Float16* __restrict__ Xh, const _Float16* __restrict__ wgT,
    const _Float16* __restrict__ wuT, _Float16* __restrict__ Hid,
    const int* __restrict__ counts, const int* __restrict__ tlist,
    const float* __restrict__ w_d, _Float16* __restrict__ wdT) {
  __shared__ _Float16 As[3][TM * BK];   // 3 x 8 KB
  __shared__ _Float16 Bg[3][TN * BK];   // 3 x 8 KB
  __shared__ _Float16 Bu[3][TN * BK];   // 3 x 8 KB
  int lin = blockIdx.x;
  if (lin >= NGEMM_UP) {
    float (*tile)[69] = reinterpret_cast<float (*)[69]>(&As[0][0]);
    transpose64(w_d, wdT, M, D, lin - NGEMM_UP, tile);
    return;
  }
  int e = lin & 7;
  int r = lin >> 3;
  int nt = r % NT_UP;
  int mt = r / NT_UP;
  int base_e, pc_e, cnt_e;
  expert_base_pc(counts, e, base_e, pc_e, cnt_e);
  if (mt * TM >= pc_e) return;
  int row0 = base_e + mt * TM;
  int n0 = nt * TN;
  int tid = threadIdx.x;
  int w = tid >> 6, lane = tid & 63;
  int lrow = lane & 15, quad = lane >> 4;
  int wr = w >> 1, wc = w & 1;
  int sr = lane >> 2;                         // staging row within 16-row group
  int c4 = lane & 3;                          // staging chunk
  int swc = ((c4 ^ ((sr >> 1) & 3))) * 8;     // pre-swizzled source chunk (halves)

  const _Float16* wg_e = wgT + (size_t)e * M * D;
  const _Float16* wu_e = wuT + (size_t)e * M * D;
  const _Float16* pA[2]; const _Float16* pG[2]; const _Float16* pU[2];
  int loff[2];
  #pragma unroll
  for (int is = 0; is < 2; ++is) {
    int grow = w * 32 + is * 16 + sr;         // tile row 0..127
    int local = mt * TM + grow;
    int trow = (local < cnt_e) ? tlist[e * T + local] : 0;  // pad-safe gather
    pA[is] = Xh   + (size_t)trow * D + swc;
    pG[is] = wg_e + (size_t)(n0 + grow) * D + swc;
    pU[is] = wu_e + (size_t)(n0 + grow) * D + swc;
    loff[is] = (w * 2 + is) * 1024;
  }

  int swr = (lrow >> 1) & 3;                  // read-side swizzle

  floatx4 accg[4][4] = {};   // [c][i]
  floatx4 accu[4][4] = {};

  auto stage = [&](int b) {
    char* a0 = (char*)&As[b][0];
    char* g0 = (char*)&Bg[b][0];
    char* u0 = (char*)&Bu[b][0];
    #pragma unroll
    for (int is = 0; is < 2; ++is) {
      gl_lds16(pA[is], a0 + loff[is]); pA[is] += BK;
      gl_lds16(pG[is], g0 + loff[is]); pG[is] += BK;
      gl_lds16(pU[is], u0 + loff[is]); pU[is] += BK;
    }
  };
  auto compute = [&](int b) {
    int kc = (quad ^ swr) * 8;
    half8 af[4];
    #pragma unroll
    for (int i = 0; i < 4; ++i)
      af[i] = *(const half8*)&As[b][(wr * 64 + i * 16 + lrow) * BK + kc];
    #pragma unroll
    for (int c = 0; c < 4; ++c) {
      int bo = (wc * 64 + c * 16 + lrow) * BK + kc;
      half8 bgc = *(const half8*)&Bg[b][bo];
      half8 buc = *(const half8*)&Bu[b][bo];
      #pragma unroll
      for (int i = 0; i < 4; ++i) {
        accg[c][i] = __builtin_amdgcn_mfma_f32_16x16x32_f16(af[i], bgc, accg[c][i], 0, 0, 0);
        accu[c][i] = __builtin_amdgcn_mfma_f32_16x16x32_f16(af[i], buc, accu[c][i], 0, 0, 0);
      }
    }
  };

  constexpr int NTK = D / BK;   // 32
  stage(0); stage(1);
  for (int k = 0; k < NTK; ++k) {
    if (k + 2 < NTK) {
      stage((k + 2) % 3);
      VMW12();
    } else if (k + 1 < NTK) {
      VMW6();
    } else {
      VMW0();
    }
    __builtin_amdgcn_sched_barrier(0);
    __builtin_amdgcn_s_barrier();
    compute(k % 3);
    __builtin_amdgcn_s_barrier();
  }

  #pragma unroll
  for (int c = 0; c < 4; ++c) {
    int col = n0 + wc * 64 + c * 16 + lrow;
    #pragma unroll
    for (int i = 0; i < 4; ++i) {
      int rowb = row0 + wr * 64 + i * 16 + quad * 4;
      #pragma unroll
      for (int reg = 0; reg < 4; ++reg) {
        float g = accg[c][i][reg], u = accu[c][i][reg];
        Hid[(size_t)(rowb + reg) * M + col] = (_Float16)(g / (1.f + expf(-g)) * u);
      }
    }
  }
}

// ---------------- down grouped GEMM -> atomic weighted combine into out -------
// 2-stage counted-vmcnt dbuf, 32KB LDS, (256,3): single-GEMM acc = 64 regs,
// should fit 3 waves/SIMD without spill (tripwire: WRITE_SIZE/VGPR).
// Epilogue: out[t][col] += p * acc (f32, atomic).  Each output element gets
// exactly 2 addends from a zeroed buffer -> order-invariant (deterministic),
// and skips the f16 Yp round-trip (better precision than separate combine).
__global__ __launch_bounds__(256, 3) void k_down(
    const _Float16* __restrict__ Hid, const _Float16* __restrict__ wdT,
    float* __restrict__ out, const int* __restrict__ counts,
    const int* __restrict__ tlist, const float* __restrict__ plist) {
  int lin = blockIdx.x;
  int e = lin & 7;
  int r = lin >> 3;
  int nt = r % NT_DN;
  int mt = r / NT_DN;
  int base_e, pc_e, cnt_e;
  expert_base_pc(counts, e, base_e, pc_e, cnt_e);
  if (mt * TM >= pc_e) return;
  int row0 = base_e + mt * TM;
  int d0 = nt * TN;
  __shared__ _Float16 As[2][TM * BK];   // 2 x 8 KB
  __shared__ _Float16 Bs[2][TN * BK];   // 2 x 8 KB
  int tid = threadIdx.x;
  int w = tid >> 6, lane = tid & 63;
  int lrow = lane & 15, quad = lane >> 4;
  int wr = w >> 1, wc = w & 1;
  int sr = lane >> 2;
  int c4 = lane & 3;
  int swc = ((c4 ^ ((sr >> 1) & 3))) * 8;

  const _Float16* wd_e = wdT + (size_t)e * D * M;
  const _Float16* pA[2]; const _Float16* pB[2];
  int loff[2];
  #pragma unroll
  for (int is = 0; is < 2; ++is) {
    int grow = w * 32 + is * 16 + sr;
    pA[is] = Hid  + (size_t)(row0 + grow) * M + swc;
    pB[is] = wd_e + (size_t)(d0   + grow) * M + swc;
    loff[is] = (w * 2 + is) * 1024;
  }

  int swr = (lrow >> 1) & 3;

  floatx4 acc[4][4] = {};

  auto stage = [&](int b) {
    char* a0 = (char*)&As[b][0];
    char* b0 = (char*)&Bs[b][0];
    #pragma unroll
    for (int is = 0; is < 2; ++is) {
      gl_lds16(pA[is], a0 + loff[is]); pA[is] += BK;
      gl_lds16(pB[is], b0 + loff[is]); pB[is] += BK;
    }
  };
  auto compute = [&](int b) {
    int kc = (quad ^ swr) * 8;
    half8 af[4];
    #pragma unroll
    for (int i = 0; i < 4; ++i)
      af[i] = *(const half8*)&As[b][(wr * 64 + i * 16 + lrow) * BK + kc];
    #pragma unroll
    for (int c = 0; c < 4; ++c) {
      half8 bc = *(const half8*)&Bs[b][(wc * 64 + c * 16 + lrow) * BK + kc];
      #pragma unroll
      for (int i = 0; i < 4; ++i)
        acc[c][i] = __builtin_amdgcn_mfma_f32_16x16x32_f16(af[i], bc, acc[c][i], 0, 0, 0);
    }
  };

  constexpr int NTK = M / BK;   // 44
  stage(0);
  int cur = 0;
  for (int k = 0; k < NTK; ++k) {
    if (k + 1 < NTK) {
      stage(cur ^ 1);
      VMW4();
    } else {
      VMW0();
    }
    __builtin_amdgcn_sched_barrier(0);
    __builtin_amdgcn_s_barrier();
    compute(cur);
    __builtin_amdgcn_s_barrier();
    cur ^= 1;
  }

  // epilogue: per-row token/prob lookup, atomic weighted accumulate
  int tI[4][4]; float pI[4][4];
  #pragma unroll
  for (int i = 0; i < 4; ++i) {
    #pragma unroll
    for (int reg = 0; reg < 4; ++reg) {
      int rl = mt * TM + wr * 64 + i * 16 + quad * 4 + reg;
      bool valid = rl < cnt_e;
      tI[i][reg] = valid ? tlist[e * T + rl] : -1;
      pI[i][reg] = valid ? plist[e * T + rl] : 0.f;
    }
  }
  #pragma unroll
  for (int c = 0; c < 4; ++c) {
    int col = d0 + wc * 64 + c * 16 + lrow;
    #pragma unroll
    for (int i = 0; i < 4; ++i) {
      #pragma unroll
      for (int reg = 0; reg < 4; ++reg) {
        if (tI[i][reg] >= 0)
          atomicAdd(&out[(size_t)tI[i][reg] * D + col], pI[i][reg] * acc[c][i][reg]);
      }
    }
  }
}

// ---------------- launch ----------------
extern "C" void kernel_launch(void* const* d_in, const int* in_sizes, int n_in,
                              void* d_out, int out_size, void* d_ws, size_t ws_size,
                              hipStream_t stream) {
  const float* x     = (const float*)d_in[0];
  const float* wgate = (const float*)d_in[1];
  const float* w_g   = (const float*)d_in[2];
  const float* w_u   = (const float*)d_in[3];
  const float* w_d   = (const float*)d_in[4];
  float* out = (float*)d_out;
  char* ws = (char*)d_ws;

  if (ws_size < WS_NEED) {
    fprintf(stderr, "kernel_launch: ws_size=%zu < needed %zu\n", ws_size, WS_NEED);
    return;
  }

  int* counts   = (int*)(ws + OFF_COUNTS);
  int* tlist    = (int*)(ws + OFF_TLIST);
  float* plist  = (float*)(ws + OFF_PLIST);
  _Float16* Xh  = (_Float16*)(ws + OFF_XH);
  _Float16* Hid = (_Float16*)(ws + OFF_HID);
  _Float16* wgT = (_Float16*)(ws + OFF_WGT);
  _Float16* wuT = (_Float16*)(ws + OFF_WUT);
  _Float16* wdT = (_Float16*)(ws + OFF_WDT);

  hipMemsetAsync(counts, 0, (size_t)E * CSTR * 4, stream);
  hipMemsetAsync(out, 0, (size_t)T * D * 4, stream);

  k_prep<<<PREP_GRID, 256, 0, stream>>>(x, wgate, w_g, w_u, Xh,
                                        wgT, wuT, counts, tlist, plist);
  k_upgate<<<UPG_GRID, 256, 0, stream>>>(Xh, wgT, wuT, Hid, counts, tlist,
                                         w_d, wdT);
  k_down<<<E * MT_MAX * NT_DN, 256, 0, stream>>>(Hid, wdT, out, counts,
                                                 tlist, plist);
}

// Round 11
// 324.703 us; speedup vs baseline: 1.0085x; 1.0085x over previous
//
#include <hip/hip_runtime.h>
#include <cstdio>

// ---------------- problem constants ----------------
constexpr int T  = 4096;       // B*S tokens
constexpr int D  = 1024;       // n_embed
constexpr int M  = 1408;       // n_moe_mlp
constexpr int E  = 8;          // experts

constexpr int TM = 128;        // token-rows per tile
constexpr int TN = 128;        // output cols per tile
constexpr int BK = 32;         // K-step
constexpr int MT_MAX = T / TM; // 32 row-tiles max per expert
constexpr int NT_UP = M / TN;  // 11
constexpr int NT_DN = D / TN;  // 8
constexpr int RCAP = T * 2 + E * TM;  // 9216 padded row capacity (Hid)

constexpr int CSTR = 64;       // per-expert counter stride in ints (256 B)
constexpr int XCV  = T / 2;    // 2048 convert+router blocks (2 tokens each)
constexpr int TPW  = E * (D / 64) * (M / 64);   // 2816 transpose tiles per weight
constexpr int PREP_GRID = XCV + 2 * TPW;        // convert+router, wg/wu transposes
constexpr int NGEMM_UP  = E * MT_MAX * NT_UP;   // 2816
constexpr int UPG_GRID  = NGEMM_UP + TPW;       // + wd transpose blocks (fill slack)

typedef _Float16 half8 __attribute__((ext_vector_type(8)));
typedef float    floatx4 __attribute__((ext_vector_type(4)));

// counted vmcnt waits (T4): never drain to 0 in the main loop.
#define VMW12() asm volatile("s_waitcnt vmcnt(12)" ::: "memory")
#define VMW6()  asm volatile("s_waitcnt vmcnt(6)"  ::: "memory")
#define VMW4()  asm volatile("s_waitcnt vmcnt(4)"  ::: "memory")
#define VMW0()  asm volatile("s_waitcnt vmcnt(0)"  ::: "memory")

// ---------------- ws layout (bytes) ----------------
constexpr size_t OFF_COUNTS = 0;                                // E*CSTR ints (2KB)
constexpr size_t OFF_TLIST  = 2048;                             // E*T ints  (128KB)
constexpr size_t OFF_PLIST  = OFF_TLIST + (size_t)E * T * 4;    // E*T floats(128KB)
constexpr size_t OFF_XH     = OFF_PLIST + (size_t)E * T * 4;    // T x D f16 (8.4MB)
constexpr size_t OFF_HID    = OFF_XH  + (size_t)T * D * 2;      // RCAP x M f16
constexpr size_t OFF_WGT    = OFF_HID + (size_t)RCAP * M * 2;   // E x M x D f16
constexpr size_t OFF_WUT    = OFF_WGT + (size_t)E * M * D * 2;
constexpr size_t OFF_WDT    = OFF_WUT + (size_t)E * M * D * 2;  // E x D x M f16
constexpr size_t WS_NEED    = OFF_WDT + (size_t)E * D * M * 2;

// async global->LDS, 16B per lane. LDS dest = wave-uniform base + lane*16;
// GLOBAL source is per-lane (enables gather + source-side swizzle).
__device__ __forceinline__ void gl_lds16(const void* g, void* l) {
  __builtin_amdgcn_global_load_lds(
      (const __attribute__((address_space(1))) unsigned int*)g,
      (__attribute__((address_space(3))) unsigned int*)l, 16, 0, 0);
}

// 8-expert padded prefix via uniform scalar loads.
__device__ __forceinline__ void expert_base_pc(const int* __restrict__ counts,
                                               int e, int& base_e, int& pc_e,
                                               int& cnt_e) {
  int b = 0; base_e = 0; pc_e = 0; cnt_e = 0;
  #pragma unroll
  for (int ee = 0; ee < E; ++ee) {
    int c = counts[ee * CSTR];
    int p = (c + TM - 1) / TM * TM;
    if (ee == e) { base_e = b; pc_e = p; cnt_e = c; }
    b += p;
  }
}

// ---------------- 64x64 f32->f16 transpose tile (round-8, verified) -----------
__device__ __forceinline__ void transpose64(
    const float* __restrict__ src, _Float16* __restrict__ dst,
    int Rr, int Cc, int j, float (*tile)[69]) {
  int ctn = Cc >> 6, rtn = Rr >> 6;
  int e   = j / (ctn * rtn);
  int rem = j - e * (ctn * rtn);
  int rt = rem / ctn, ct = rem - rt * ctn;
  int t = threadIdx.x;
  int lr = t >> 2;            // 0..63 source row
  int lc = (t & 3) * 16;      // 16-float chunk
  const float* s = src + ((size_t)e * Rr + rt * 64 + lr) * Cc + ct * 64 + lc;
  float4 v0 = *(const float4*)(s + 0);
  float4 v1 = *(const float4*)(s + 4);
  float4 v2 = *(const float4*)(s + 8);
  float4 v3 = *(const float4*)(s + 12);
  float* tr = &tile[lr][lc];
  tr[0]  = v0.x; tr[1]  = v0.y; tr[2]  = v0.z; tr[3]  = v0.w;
  tr[4]  = v1.x; tr[5]  = v1.y; tr[6]  = v1.z; tr[7]  = v1.w;
  tr[8]  = v2.x; tr[9]  = v2.y; tr[10] = v2.z; tr[11] = v2.w;
  tr[12] = v3.x; tr[13] = v3.y; tr[14] = v3.z; tr[15] = v3.w;
  __syncthreads();
  #pragma unroll
  for (int rep = 0; rep < 2; ++rep) {
    int s2 = t + rep * 256;
    int oc = s2 >> 3;         // 0..63 output row (= source col)
    int sl = s2 & 7;          // 16B segment within output row
    half8 o;
    #pragma unroll
    for (int q = 0; q < 8; ++q) o[q] = (_Float16)tile[sl * 8 + q][oc];
    *(half8*)(dst + ((size_t)e * Cc + ct * 64 + oc) * Rr + rt * 64 + sl * 8) = o;
  }
}

// ---------------- fused prep: (x->f16 convert + router) + wg/wu transposes ----
__global__ __launch_bounds__(256) void k_prep(
    const float* __restrict__ x, const float* __restrict__ wgate,
    const float* __restrict__ w_g, const float* __restrict__ w_u,
    _Float16* __restrict__ Xh,
    _Float16* __restrict__ wgT, _Float16* __restrict__ wuT,
    int* __restrict__ counts, int* __restrict__ tlist,
    float* __restrict__ plist) {
  __shared__ float tile[64][69];
  __shared__ float s_red[4][8];
  int bid = blockIdx.x;

  if (bid < XCV) {
    int tid = threadIdx.x;
    int row  = tid >> 7;             // 0 or 1
    int t    = bid * 2 + row;
    int dpos = (tid & 127) * 8;      // 0..1023
    int wv = tid >> 6, lane = tid & 63;
    const float* xr = x + (size_t)t * D + dpos;
    float4 v0 = *(const float4*)(xr);
    float4 v1 = *(const float4*)(xr + 4);
    half8 h;
    h[0] = (_Float16)v0.x; h[1] = (_Float16)v0.y;
    h[2] = (_Float16)v0.z; h[3] = (_Float16)v0.w;
    h[4] = (_Float16)v1.x; h[5] = (_Float16)v1.y;
    h[6] = (_Float16)v1.z; h[7] = (_Float16)v1.w;
    *(half8*)(Xh + (size_t)t * D + dpos) = h;
    // router partials: 8 elems x 8 experts
    float xv[8] = {v0.x, v0.y, v0.z, v0.w, v1.x, v1.y, v1.z, v1.w};
    float acc[8] = {0.f,0.f,0.f,0.f,0.f,0.f,0.f,0.f};
    #pragma unroll
    for (int j = 0; j < 8; ++j) {
      const float4* wr2 = (const float4*)(wgate + (size_t)(dpos + j) * E);
      float4 w0 = wr2[0], w1 = wr2[1];
      acc[0] += xv[j] * w0.x; acc[1] += xv[j] * w0.y;
      acc[2] += xv[j] * w0.z; acc[3] += xv[j] * w0.w;
      acc[4] += xv[j] * w1.x; acc[5] += xv[j] * w1.y;
      acc[6] += xv[j] * w1.z; acc[7] += xv[j] * w1.w;
    }
    #pragma unroll
    for (int e = 0; e < 8; ++e) {
      #pragma unroll
      for (int off = 32; off; off >>= 1) acc[e] += __shfl_xor(acc[e], off, 64);
    }
    if (lane == 0) {
      #pragma unroll
      for (int e = 0; e < 8; ++e) s_red[wv][e] = acc[e];
    }
    __syncthreads();
    if ((tid & 127) == 0) {
      int wb = row * 2;
      float sc[8];
      #pragma unroll
      for (int e = 0; e < 8; ++e) sc[e] = s_red[wb][e] + s_red[wb + 1][e];
      int i0 = 0; float s0 = sc[0];
      #pragma unroll
      for (int e = 1; e < 8; ++e) if (sc[e] > s0) { s0 = sc[e]; i0 = e; }
      int i1 = -1; float s1 = -1e30f;
      #pragma unroll
      for (int e = 0; e < 8; ++e) if (e != i0 && sc[e] > s1) { s1 = sc[e]; i1 = e; }
      float p0 = 1.f / (1.f + expf(s1 - s0));
      float p1 = 1.f - p0;
      int q0 = atomicAdd(&counts[i0 * CSTR], 1);
      int q1 = atomicAdd(&counts[i1 * CSTR], 1);
      tlist[i0 * T + q0] = t; plist[i0 * T + q0] = p0;
      tlist[i1 * T + q1] = t; plist[i1 * T + q1] = p1;
    }
    return;
  }

  // ---- wg / wu transpose-convert ----
  int i = bid - XCV;
  if (i < TPW) transpose64(w_g, wgT, D, M, i, tile);
  else         transpose64(w_u, wuT, D, M, i - TPW, tile);
}

// ---------------- fused gate+up grouped GEMM + SiLU (+ wd transpose blocks) ---
// GEMM body identical to round-8 (verified): 3-buffer counted-vmcnt pipeline,
// gather-A from Xh, both-sides LDS swizzle, wd-transpose piggyback.
__global__ __launch_bounds__(256, 2) void k_upgate(
    const _Float16* __restrict__ Xh, const _Float16* __restrict__ wgT,
    const _Float16* __restrict__ wuT, _Float16* __restrict__ Hid,
    const int* __restrict__ counts, const int* __restrict__ tlist,
    const float* __restrict__ w_d, _Float16* __restrict__ wdT) {
  __shared__ _Float16 As[3][TM * BK];   // 3 x 8 KB
  __shared__ _Float16 Bg[3][TN * BK];   // 3 x 8 KB
  __shared__ _Float16 Bu[3][TN * BK];   // 3 x 8 KB
  int lin = blockIdx.x;
  if (lin >= NGEMM_UP) {
    float (*tile)[69] = reinterpret_cast<float (*)[69]>(&As[0][0]);
    transpose64(w_d, wdT, M, D, lin - NGEMM_UP, tile);
    return;
  }
  int e = lin & 7;
  int r = lin >> 3;
  int nt = r % NT_UP;
  int mt = r / NT_UP;
  int base_e, pc_e, cnt_e;
  expert_base_pc(counts, e, base_e, pc_e, cnt_e);
  if (mt * TM >= pc_e) return;
  int row0 = base_e + mt * TM;
  int n0 = nt * TN;
  int tid = threadIdx.x;
  int w = tid >> 6, lane = tid & 63;
  int lrow = lane & 15, quad = lane >> 4;
  int wr = w >> 1, wc = w & 1;
  int sr = lane >> 2;                         // staging row within 16-row group
  int c4 = lane & 3;                          // staging chunk
  int swc = ((c4 ^ ((sr >> 1) & 3))) * 8;     // pre-swizzled source chunk (halves)

  const _Float16* wg_e = wgT + (size_t)e * M * D;
  const _Float16* wu_e = wuT + (size_t)e * M * D;
  const _Float16* pA[2]; const _Float16* pG[2]; const _Float16* pU[2];
  int loff[2];
  #pragma unroll
  for (int is = 0; is < 2; ++is) {
    int grow = w * 32 + is * 16 + sr;         // tile row 0..127
    int local = mt * TM + grow;
    int trow = (local < cnt_e) ? tlist[e * T + local] : 0;  // pad-safe gather
    pA[is] = Xh   + (size_t)trow * D + swc;
    pG[is] = wg_e + (size_t)(n0 + grow) * D + swc;
    pU[is] = wu_e + (size_t)(n0 + grow) * D + swc;
    loff[is] = (w * 2 + is) * 1024;
  }

  int swr = (lrow >> 1) & 3;                  // read-side swizzle

  floatx4 accg[4][4] = {};   // [c][i]
  floatx4 accu[4][4] = {};

  auto stage = [&](int b) {
    char* a0 = (char*)&As[b][0];
    char* g0 = (char*)&Bg[b][0];
    char* u0 = (char*)&Bu[b][0];
    #pragma unroll
    for (int is = 0; is < 2; ++is) {
      gl_lds16(pA[is], a0 + loff[is]); pA[is] += BK;
      gl_lds16(pG[is], g0 + loff[is]); pG[is] += BK;
      gl_lds16(pU[is], u0 + loff[is]); pU[is] += BK;
    }
  };
  auto compute = [&](int b) {
    int kc = (quad ^ swr) * 8;
    half8 af[4];
    #pragma unroll
    for (int i = 0; i < 4; ++i)
      af[i] = *(const half8*)&As[b][(wr * 64 + i * 16 + lrow) * BK + kc];
    #pragma unroll
    for (int c = 0; c < 4; ++c) {
      int bo = (wc * 64 + c * 16 + lrow) * BK + kc;
      half8 bgc = *(const half8*)&Bg[b][bo];
      half8 buc = *(const half8*)&Bu[b][bo];
      #pragma unroll
      for (int i = 0; i < 4; ++i) {
        accg[c][i] = __builtin_amdgcn_mfma_f32_16x16x32_f16(af[i], bgc, accg[c][i], 0, 0, 0);
        accu[c][i] = __builtin_amdgcn_mfma_f32_16x16x32_f16(af[i], buc, accu[c][i], 0, 0, 0);
      }
    }
  };

  constexpr int NTK = D / BK;   // 32
  stage(0); stage(1);
  for (int k = 0; k < NTK; ++k) {
    if (k + 2 < NTK) {
      stage((k + 2) % 3);
      VMW12();
    } else if (k + 1 < NTK) {
      VMW6();
    } else {
      VMW0();
    }
    __builtin_amdgcn_sched_barrier(0);
    __builtin_amdgcn_s_barrier();
    compute(k % 3);
    __builtin_amdgcn_s_barrier();
  }

  #pragma unroll
  for (int c = 0; c < 4; ++c) {
    int col = n0 + wc * 64 + c * 16 + lrow;
    #pragma unroll
    for (int i = 0; i < 4; ++i) {
      int rowb = row0 + wr * 64 + i * 16 + quad * 4;
      #pragma unroll
      for (int reg = 0; reg < 4; ++reg) {
        float g = accg[c][i][reg], u = accu[c][i][reg];
        Hid[(size_t)(rowb + reg) * M + col] = (_Float16)(g / (1.f + expf(-g)) * u);
      }
    }
  }
}

// ---------------- down grouped GEMM -> atomic weighted combine into out -------
// (256,2): round-10's (256,3) forced accumulator+epilogue spill (round-2
// signature, ~40us regression). Budget 256 regs/wave at 2 waves/EU: 64 acc +
// 32 epilogue tI/pI + addressing fits with headroom.
// Epilogue: out[t][col] += p * acc (f32, atomic); 2 addends per element from
// a zeroed buffer -> order-invariant (deterministic), skips f16 Yp round-trip.
__global__ __launch_bounds__(256, 2) void k_down(
    const _Float16* __restrict__ Hid, const _Float16* __restrict__ wdT,
    float* __restrict__ out, const int* __restrict__ counts,
    const int* __restrict__ tlist, const float* __restrict__ plist) {
  int lin = blockIdx.x;
  int e = lin & 7;
  int r = lin >> 3;
  int nt = r % NT_DN;
  int mt = r / NT_DN;
  int base_e, pc_e, cnt_e;
  expert_base_pc(counts, e, base_e, pc_e, cnt_e);
  if (mt * TM >= pc_e) return;
  int row0 = base_e + mt * TM;
  int d0 = nt * TN;
  __shared__ _Float16 As[2][TM * BK];   // 2 x 8 KB
  __shared__ _Float16 Bs[2][TN * BK];   // 2 x 8 KB
  int tid = threadIdx.x;
  int w = tid >> 6, lane = tid & 63;
  int lrow = lane & 15, quad = lane >> 4;
  int wr = w >> 1, wc = w & 1;
  int sr = lane >> 2;
  int c4 = lane & 3;
  int swc = ((c4 ^ ((sr >> 1) & 3))) * 8;

  const _Float16* wd_e = wdT + (size_t)e * D * M;
  const _Float16* pA[2]; const _Float16* pB[2];
  int loff[2];
  #pragma unroll
  for (int is = 0; is < 2; ++is) {
    int grow = w * 32 + is * 16 + sr;
    pA[is] = Hid  + (size_t)(row0 + grow) * M + swc;
    pB[is] = wd_e + (size_t)(d0   + grow) * M + swc;
    loff[is] = (w * 2 + is) * 1024;
  }

  int swr = (lrow >> 1) & 3;

  floatx4 acc[4][4] = {};

  auto stage = [&](int b) {
    char* a0 = (char*)&As[b][0];
    char* b0 = (char*)&Bs[b][0];
    #pragma unroll
    for (int is = 0; is < 2; ++is) {
      gl_lds16(pA[is], a0 + loff[is]); pA[is] += BK;
      gl_lds16(pB[is], b0 + loff[is]); pB[is] += BK;
    }
  };
  auto compute = [&](int b) {
    int kc = (quad ^ swr) * 8;
    half8 af[4];
    #pragma unroll
    for (int i = 0; i < 4; ++i)
      af[i] = *(const half8*)&As[b][(wr * 64 + i * 16 + lrow) * BK + kc];
    #pragma unroll
    for (int c = 0; c < 4; ++c) {
      half8 bc = *(const half8*)&Bs[b][(wc * 64 + c * 16 + lrow) * BK + kc];
      #pragma unroll
      for (int i = 0; i < 4; ++i)
        acc[c][i] = __builtin_amdgcn_mfma_f32_16x16x32_f16(af[i], bc, acc[c][i], 0, 0, 0);
    }
  };

  constexpr int NTK = M / BK;   // 44
  stage(0);
  int cur = 0;
  for (int k = 0; k < NTK; ++k) {
    if (k + 1 < NTK) {
      stage(cur ^ 1);
      VMW4();
    } else {
      VMW0();
    }
    __builtin_amdgcn_sched_barrier(0);
    __builtin_amdgcn_s_barrier();
    compute(cur);
    __builtin_amdgcn_s_barrier();
    cur ^= 1;
  }

  // epilogue: per-row token/prob lookup, atomic weighted accumulate
  int tI[4][4]; float pI[4][4];
  #pragma unroll
  for (int i = 0; i < 4; ++i) {
    #pragma unroll
    for (int reg = 0; reg < 4; ++reg) {
      int rl = mt * TM + wr * 64 + i * 16 + quad * 4 + reg;
      bool valid = rl < cnt_e;
      tI[i][reg] = valid ? tlist[e * T + rl] : -1;
      pI[i][reg] = valid ? plist[e * T + rl] : 0.f;
    }
  }
  #pragma unroll
  for (int c = 0; c < 4; ++c) {
    int col = d0 + wc * 64 + c * 16 + lrow;
    #pragma unroll
    for (int i = 0; i < 4; ++i) {
      #pragma unroll
      for (int reg = 0; reg < 4; ++reg) {
        if (tI[i][reg] >= 0)
          atomicAdd(&out[(size_t)tI[i][reg] * D + col], pI[i][reg] * acc[c][i][reg]);
      }
    }
  }
}

// ---------------- launch ----------------
extern "C" void kernel_launch(void* const* d_in, const int* in_sizes, int n_in,
                              void* d_out, int out_size, void* d_ws, size_t ws_size,
                              hipStream_t stream) {
  const float* x     = (const float*)d_in[0];
  const float* wgate = (const float*)d_in[1];
  const float* w_g   = (const float*)d_in[2];
  const float* w_u   = (const float*)d_in[3];
  const float* w_d   = (const float*)d_in[4];
  float* out = (float*)d_out;
  char* ws = (char*)d_ws;

  if (ws_size < WS_NEED) {
    fprintf(stderr, "kernel_launch: ws_size=%zu < needed %zu\n", ws_size, WS_NEED);
    return;
  }

  int* counts   = (int*)(ws + OFF_COUNTS);
  int* tlist    = (int*)(ws + OFF_TLIST);
  float* plist  = (float*)(ws + OFF_PLIST);
  _Float16* Xh  = (_Float16*)(ws + OFF_XH);
  _Float16* Hid = (_Float16*)(ws + OFF_HID);
  _Float16* wgT = (_Float16*)(ws + OFF_WGT);
  _Float16* wuT = (_Float16*)(ws + OFF_WUT);
  _Float16* wdT = (_Float16*)(ws + OFF_WDT);

  hipMemsetAsync(counts, 0, (size_t)E * CSTR * 4, stream);
  hipMemsetAsync(out, 0, (size_t)T * D * 4, stream);

  k_prep<<<PREP_GRID, 256, 0, stream>>>(x, wgate, w_g, w_u, Xh,
                                        wgT, wuT, counts, tlist, plist);
  k_upgate<<<UPG_GRID, 256, 0, stream>>>(Xh, wgT, wuT, Hid, counts, tlist,
                                         w_d, wdT);
  k_down<<<E * MT_MAX * NT_DN, 256, 0, stream>>>(Hid, wdT, out, counts,
                                                 tlist, plist);
}

// Round 12
// 299.840 us; speedup vs baseline: 1.0921x; 1.0829x over previous
//
#include <hip/hip_runtime.h>
#include <cstdio>

// ---------------- problem constants ----------------
constexpr int T  = 4096;       // B*S tokens
constexpr int D  = 1024;       // n_embed
constexpr int M  = 1408;       // n_moe_mlp
constexpr int E  = 8;          // experts

constexpr int TM = 128;        // token-rows per tile
constexpr int TN = 128;        // output cols per tile
constexpr int BK = 32;         // K-step
constexpr int MT_MAX = T / TM; // 32 row-tiles max per expert
constexpr int NT_UP = M / TN;  // 11
constexpr int NT_DN = D / TN;  // 8
constexpr int RCAP = T * 2 + E * TM;  // 9216 padded row capacity

constexpr int CSTR = 64;       // per-expert counter stride in ints (256 B)
constexpr int XCV  = T / 2;    // 2048 convert+router blocks (2 tokens each)
constexpr int TPW  = E * (D / 64) * (M / 64);   // 2816 transpose tiles per weight
constexpr int PREP_GRID = XCV + 2 * TPW;        // convert+router, wg/wu transposes
constexpr int NGEMM_UP  = E * MT_MAX * NT_UP;   // 2816
constexpr int UPG_GRID  = NGEMM_UP + TPW;       // + wd transpose blocks (fill slack)

typedef _Float16 half8 __attribute__((ext_vector_type(8)));
typedef _Float16 half4 __attribute__((ext_vector_type(4)));
typedef float    floatx4 __attribute__((ext_vector_type(4)));

// counted vmcnt waits (T4): never drain to 0 in the main loop.
#define VMW12() asm volatile("s_waitcnt vmcnt(12)" ::: "memory")
#define VMW8()  asm volatile("s_waitcnt vmcnt(8)"  ::: "memory")
#define VMW6()  asm volatile("s_waitcnt vmcnt(6)"  ::: "memory")
#define VMW4()  asm volatile("s_waitcnt vmcnt(4)"  ::: "memory")
#define VMW0()  asm volatile("s_waitcnt vmcnt(0)"  ::: "memory")

// ---------------- ws layout (bytes) ----------------
constexpr size_t OFF_COUNTS = 0;                                // E*CSTR ints (2KB)
constexpr size_t OFF_TLIST  = 2048;                             // E*T ints  (128KB)
constexpr size_t OFF_T2E    = OFF_TLIST + (size_t)E * T * 4;    // 2T ints
constexpr size_t OFF_T2POS  = OFF_T2E   + (size_t)2 * T * 4;
constexpr size_t OFF_T2P    = OFF_T2POS + (size_t)2 * T * 4;
constexpr size_t OFF_XG     = OFF_T2P   + (size_t)2 * T * 4;    // RCAP x D f16 (Xh rows 0..T-1; reused as Yp)
constexpr size_t OFF_HID    = OFF_XG  + (size_t)RCAP * D * 2;   // RCAP x M f16
constexpr size_t OFF_WGT    = OFF_HID + (size_t)RCAP * M * 2;   // E x M x D f16
constexpr size_t OFF_WUT    = OFF_WGT + (size_t)E * M * D * 2;
constexpr size_t OFF_WDT    = OFF_WUT + (size_t)E * M * D * 2;  // E x D x M f16
constexpr size_t WS_NEED    = OFF_WDT + (size_t)E * D * M * 2;

// async global->LDS, 16B per lane. LDS dest = wave-uniform base + lane*16;
// GLOBAL source is per-lane (enables gather + source-side swizzle).
__device__ __forceinline__ void gl_lds16(const void* g, void* l) {
  __builtin_amdgcn_global_load_lds(
      (const __attribute__((address_space(1))) unsigned int*)g,
      (__attribute__((address_space(3))) unsigned int*)l, 16, 0, 0);
}

// 8-expert padded prefix via uniform scalar loads.
__device__ __forceinline__ void expert_base_pc(const int* __restrict__ counts,
                                               int e, int& base_e, int& pc_e,
                                               int& cnt_e) {
  int b = 0; base_e = 0; pc_e = 0; cnt_e = 0;
  #pragma unroll
  for (int ee = 0; ee < E; ++ee) {
    int c = counts[ee * CSTR];
    int p = (c + TM - 1) / TM * TM;
    if (ee == e) { base_e = b; pc_e = p; cnt_e = c; }
    b += p;
  }
}

// ---------------- 64x64 f32->f16 transpose tile (round-8, verified) -----------
__device__ __forceinline__ void transpose64(
    const float* __restrict__ src, _Float16* __restrict__ dst,
    int Rr, int Cc, int j, float (*tile)[69]) {
  int ctn = Cc >> 6, rtn = Rr >> 6;
  int e   = j / (ctn * rtn);
  int rem = j - e * (ctn * rtn);
  int rt = rem / ctn, ct = rem - rt * ctn;
  int t = threadIdx.x;
  int lr = t >> 2;            // 0..63 source row
  int lc = (t & 3) * 16;      // 16-float chunk
  const float* s = src + ((size_t)e * Rr + rt * 64 + lr) * Cc + ct * 64 + lc;
  float4 v0 = *(const float4*)(s + 0);
  float4 v1 = *(const float4*)(s + 4);
  float4 v2 = *(const float4*)(s + 8);
  float4 v3 = *(const float4*)(s + 12);
  float* tr = &tile[lr][lc];
  tr[0]  = v0.x; tr[1]  = v0.y; tr[2]  = v0.z; tr[3]  = v0.w;
  tr[4]  = v1.x; tr[5]  = v1.y; tr[6]  = v1.z; tr[7]  = v1.w;
  tr[8]  = v2.x; tr[9]  = v2.y; tr[10] = v2.z; tr[11] = v2.w;
  tr[12] = v3.x; tr[13] = v3.y; tr[14] = v3.z; tr[15] = v3.w;
  __syncthreads();
  #pragma unroll
  for (int rep = 0; rep < 2; ++rep) {
    int s2 = t + rep * 256;
    int oc = s2 >> 3;         // 0..63 output row (= source col)
    int sl = s2 & 7;          // 16B segment within output row
    half8 o;
    #pragma unroll
    for (int q = 0; q < 8; ++q) o[q] = (_Float16)tile[sl * 8 + q][oc];
    *(half8*)(dst + ((size_t)e * Cc + ct * 64 + oc) * Rr + rt * 64 + sl * 8) = o;
  }
}

// ---------------- fused prep: (x->f16 convert + router) + wg/wu transposes ----
// Convert blocks each own 2 token rows; router dot from the SAME loaded values
// (no x re-read).  Emits tlist (slot->token) for upgate's gather AND
// t2e/t2pos/t2p (token->expert/slot/prob) for the combine.
__global__ __launch_bounds__(256) void k_prep(
    const float* __restrict__ x, const float* __restrict__ wgate,
    const float* __restrict__ w_g, const float* __restrict__ w_u,
    _Float16* __restrict__ Xh,
    _Float16* __restrict__ wgT, _Float16* __restrict__ wuT,
    int* __restrict__ counts, int* __restrict__ tlist,
    int* __restrict__ t2e, int* __restrict__ t2pos, float* __restrict__ t2p) {
  __shared__ float tile[64][69];
  __shared__ float s_red[4][8];
  int bid = blockIdx.x;

  if (bid < XCV) {
    int tid = threadIdx.x;
    int row  = tid >> 7;             // 0 or 1
    int t    = bid * 2 + row;
    int dpos = (tid & 127) * 8;      // 0..1023
    int wv = tid >> 6, lane = tid & 63;
    const float* xr = x + (size_t)t * D + dpos;
    float4 v0 = *(const float4*)(xr);
    float4 v1 = *(const float4*)(xr + 4);
    half8 h;
    h[0] = (_Float16)v0.x; h[1] = (_Float16)v0.y;
    h[2] = (_Float16)v0.z; h[3] = (_Float16)v0.w;
    h[4] = (_Float16)v1.x; h[5] = (_Float16)v1.y;
    h[6] = (_Float16)v1.z; h[7] = (_Float16)v1.w;
    *(half8*)(Xh + (size_t)t * D + dpos) = h;
    // router partials: 8 elems x 8 experts
    float xv[8] = {v0.x, v0.y, v0.z, v0.w, v1.x, v1.y, v1.z, v1.w};
    float acc[8] = {0.f,0.f,0.f,0.f,0.f,0.f,0.f,0.f};
    #pragma unroll
    for (int j = 0; j < 8; ++j) {
      const float4* wr2 = (const float4*)(wgate + (size_t)(dpos + j) * E);
      float4 w0 = wr2[0], w1 = wr2[1];
      acc[0] += xv[j] * w0.x; acc[1] += xv[j] * w0.y;
      acc[2] += xv[j] * w0.z; acc[3] += xv[j] * w0.w;
      acc[4] += xv[j] * w1.x; acc[5] += xv[j] * w1.y;
      acc[6] += xv[j] * w1.z; acc[7] += xv[j] * w1.w;
    }
    #pragma unroll
    for (int e = 0; e < 8; ++e) {
      #pragma unroll
      for (int off = 32; off; off >>= 1) acc[e] += __shfl_xor(acc[e], off, 64);
    }
    if (lane == 0) {
      #pragma unroll
      for (int e = 0; e < 8; ++e) s_red[wv][e] = acc[e];
    }
    __syncthreads();
    if ((tid & 127) == 0) {
      int wb = row * 2;
      float sc[8];
      #pragma unroll
      for (int e = 0; e < 8; ++e) sc[e] = s_red[wb][e] + s_red[wb + 1][e];
      int i0 = 0; float s0 = sc[0];
      #pragma unroll
      for (int e = 1; e < 8; ++e) if (sc[e] > s0) { s0 = sc[e]; i0 = e; }
      int i1 = -1; float s1 = -1e30f;
      #pragma unroll
      for (int e = 0; e < 8; ++e) if (e != i0 && sc[e] > s1) { s1 = sc[e]; i1 = e; }
      float p0 = 1.f / (1.f + expf(s1 - s0));
      float p1 = 1.f - p0;
      int q0 = atomicAdd(&counts[i0 * CSTR], 1);
      int q1 = atomicAdd(&counts[i1 * CSTR], 1);
      tlist[i0 * T + q0] = t;
      tlist[i1 * T + q1] = t;
      t2e[2 * t]     = i0; t2pos[2 * t]     = q0; t2p[2 * t]     = p0;
      t2e[2 * t + 1] = i1; t2pos[2 * t + 1] = q1; t2p[2 * t + 1] = p1;
    }
    return;
  }

  // ---- wg / wu transpose-convert ----
  int i = bid - XCV;
  if (i < TPW) transpose64(w_g, wgT, D, M, i, tile);
  else         transpose64(w_u, wuT, D, M, i - TPW, tile);
}

// ---------------- fused gate+up grouped GEMM + SiLU (+ wd transpose blocks) ---
// GEMM body identical to round-8 (verified): 3-buffer counted-vmcnt pipeline,
// gather-A from Xh, both-sides LDS swizzle, wd-transpose piggyback.
__global__ __launch_bounds__(256, 2) void k_upgate(
    const _Float16* __restrict__ Xh, const _Float16* __restrict__ wgT,
    const _Float16* __restrict__ wuT, _Float16* __restrict__ Hid,
    const int* __restrict__ counts, const int* __restrict__ tlist,
    const float* __restrict__ w_d, _Float16* __restrict__ wdT) {
  __shared__ _Float16 As[3][TM * BK];   // 3 x 8 KB
  __shared__ _Float16 Bg[3][TN * BK];   // 3 x 8 KB
  __shared__ _Float16 Bu[3][TN * BK];   // 3 x 8 KB
  int lin = blockIdx.x;
  if (lin >= NGEMM_UP) {
    float (*tile)[69] = reinterpret_cast<float (*)[69]>(&As[0][0]);
    transpose64(w_d, wdT, M, D, lin - NGEMM_UP, tile);
    return;
  }
  int e = lin & 7;
  int r = lin >> 3;
  int nt = r % NT_UP;
  int mt = r / NT_UP;
  int base_e, pc_e, cnt_e;
  expert_base_pc(counts, e, base_e, pc_e, cnt_e);
  if (mt * TM >= pc_e) return;
  int row0 = base_e + mt * TM;
  int n0 = nt * TN;
  int tid = threadIdx.x;
  int w = tid >> 6, lane = tid & 63;
  int lrow = lane & 15, quad = lane >> 4;
  int wr = w >> 1, wc = w & 1;
  int sr = lane >> 2;                         // staging row within 16-row group
  int c4 = lane & 3;                          // staging chunk
  int swc = ((c4 ^ ((sr >> 1) & 3))) * 8;     // pre-swizzled source chunk (halves)

  const _Float16* wg_e = wgT + (size_t)e * M * D;
  const _Float16* wu_e = wuT + (size_t)e * M * D;
  const _Float16* pA[2]; const _Float16* pG[2]; const _Float16* pU[2];
  int loff[2];
  #pragma unroll
  for (int is = 0; is < 2; ++is) {
    int grow = w * 32 + is * 16 + sr;         // tile row 0..127
    int local = mt * TM + grow;
    int trow = (local < cnt_e) ? tlist[e * T + local] : 0;  // pad-safe gather
    pA[is] = Xh   + (size_t)trow * D + swc;
    pG[is] = wg_e + (size_t)(n0 + grow) * D + swc;
    pU[is] = wu_e + (size_t)(n0 + grow) * D + swc;
    loff[is] = (w * 2 + is) * 1024;
  }

  int swr = (lrow >> 1) & 3;                  // read-side swizzle

  floatx4 accg[4][4] = {};   // [c][i]
  floatx4 accu[4][4] = {};

  auto stage = [&](int b) {
    char* a0 = (char*)&As[b][0];
    char* g0 = (char*)&Bg[b][0];
    char* u0 = (char*)&Bu[b][0];
    #pragma unroll
    for (int is = 0; is < 2; ++is) {
      gl_lds16(pA[is], a0 + loff[is]); pA[is] += BK;
      gl_lds16(pG[is], g0 + loff[is]); pG[is] += BK;
      gl_lds16(pU[is], u0 + loff[is]); pU[is] += BK;
    }
  };
  auto compute = [&](int b) {
    int kc = (quad ^ swr) * 8;
    half8 af[4];
    #pragma unroll
    for (int i = 0; i < 4; ++i)
      af[i] = *(const half8*)&As[b][(wr * 64 + i * 16 + lrow) * BK + kc];
    #pragma unroll
    for (int c = 0; c < 4; ++c) {
      int bo = (wc * 64 + c * 16 + lrow) * BK + kc;
      half8 bgc = *(const half8*)&Bg[b][bo];
      half8 buc = *(const half8*)&Bu[b][bo];
      #pragma unroll
      for (int i = 0; i < 4; ++i) {
        accg[c][i] = __builtin_amdgcn_mfma_f32_16x16x32_f16(af[i], bgc, accg[c][i], 0, 0, 0);
        accu[c][i] = __builtin_amdgcn_mfma_f32_16x16x32_f16(af[i], buc, accu[c][i], 0, 0, 0);
      }
    }
  };

  constexpr int NTK = D / BK;   // 32
  stage(0); stage(1);
  for (int k = 0; k < NTK; ++k) {
    if (k + 2 < NTK) {
      stage((k + 2) % 3);
      VMW12();
    } else if (k + 1 < NTK) {
      VMW6();
    } else {
      VMW0();
    }
    __builtin_amdgcn_sched_barrier(0);
    __builtin_amdgcn_s_barrier();
    compute(k % 3);
    __builtin_amdgcn_s_barrier();
  }

  #pragma unroll
  for (int c = 0; c < 4; ++c) {
    int col = n0 + wc * 64 + c * 16 + lrow;
    #pragma unroll
    for (int i = 0; i < 4; ++i) {
      int rowb = row0 + wr * 64 + i * 16 + quad * 4;
      #pragma unroll
      for (int reg = 0; reg < 4; ++reg) {
        float g = accg[c][i][reg], u = accu[c][i][reg];
        Hid[(size_t)(rowb + reg) * M + col] = (_Float16)(g / (1.f + expf(-g)) * u);
      }
    }
  }
}

// ---------------- down grouped GEMM -> per-slot rows Yp (round-8, verified) ---
// 3-buffer counted-vmcnt pipeline; writes f16 Yp rows (no atomics — round
// 9-11 showed the 8.4M-atomic combine costs ~36us net vs this structure).
__global__ __launch_bounds__(256, 2) void k_down(
    const _Float16* __restrict__ Hid, const _Float16* __restrict__ wdT,
    _Float16* __restrict__ Yp, const int* __restrict__ counts) {
  int lin = blockIdx.x;
  int e = lin & 7;
  int r = lin >> 3;
  int nt = r % NT_DN;
  int mt = r / NT_DN;
  int base_e, pc_e, cnt_e;
  expert_base_pc(counts, e, base_e, pc_e, cnt_e);
  if (mt * TM >= pc_e) return;
  int row0 = base_e + mt * TM;
  int d0 = nt * TN;
  __shared__ _Float16 As[3][TM * BK];   // 3 x 8 KB
  __shared__ _Float16 Bs[3][TN * BK];   // 3 x 8 KB
  int tid = threadIdx.x;
  int w = tid >> 6, lane = tid & 63;
  int lrow = lane & 15, quad = lane >> 4;
  int wr = w >> 1, wc = w & 1;
  int sr = lane >> 2;
  int c4 = lane & 3;
  int swc = ((c4 ^ ((sr >> 1) & 3))) * 8;

  const _Float16* wd_e = wdT + (size_t)e * D * M;
  const _Float16* pA[2]; const _Float16* pB[2];
  int loff[2];
  #pragma unroll
  for (int is = 0; is < 2; ++is) {
    int grow = w * 32 + is * 16 + sr;
    pA[is] = Hid  + (size_t)(row0 + grow) * M + swc;
    pB[is] = wd_e + (size_t)(d0   + grow) * M + swc;
    loff[is] = (w * 2 + is) * 1024;
  }

  int swr = (lrow >> 1) & 3;

  floatx4 acc[4][4] = {};

  auto stage = [&](int b) {
    char* a0 = (char*)&As[b][0];
    char* b0 = (char*)&Bs[b][0];
    #pragma unroll
    for (int is = 0; is < 2; ++is) {
      gl_lds16(pA[is], a0 + loff[is]); pA[is] += BK;
      gl_lds16(pB[is], b0 + loff[is]); pB[is] += BK;
    }
  };
  auto compute = [&](int b) {
    int kc = (quad ^ swr) * 8;
    half8 af[4];
    #pragma unroll
    for (int i = 0; i < 4; ++i)
      af[i] = *(const half8*)&As[b][(wr * 64 + i * 16 + lrow) * BK + kc];
    #pragma unroll
    for (int c = 0; c < 4; ++c) {
      half8 bc = *(const half8*)&Bs[b][(wc * 64 + c * 16 + lrow) * BK + kc];
      #pragma unroll
      for (int i = 0; i < 4; ++i)
        acc[c][i] = __builtin_amdgcn_mfma_f32_16x16x32_f16(af[i], bc, acc[c][i], 0, 0, 0);
    }
  };

  constexpr int NTK = M / BK;   // 44
  stage(0); stage(1);
  for (int k = 0; k < NTK; ++k) {
    if (k + 2 < NTK) {
      stage((k + 2) % 3);
      VMW8();
    } else if (k + 1 < NTK) {
      VMW4();
    } else {
      VMW0();
    }
    __builtin_amdgcn_sched_barrier(0);
    __builtin_amdgcn_s_barrier();
    compute(k % 3);
    __builtin_amdgcn_s_barrier();
  }

  #pragma unroll
  for (int c = 0; c < 4; ++c) {
    int col = d0 + wc * 64 + c * 16 + lrow;
    #pragma unroll
    for (int i = 0; i < 4; ++i) {
      int rowb = row0 + wr * 64 + i * 16 + quad * 4;
      #pragma unroll
      for (int reg = 0; reg < 4; ++reg)
        Yp[(size_t)(rowb + reg) * D + col] = (_Float16)acc[c][i][reg];
    }
  }
}

// ---------------- combine: y[t] = p0*Yp[r0] + p1*Yp[r1] ----------------
__global__ __launch_bounds__(256) void k_combine(
    const _Float16* __restrict__ Yp, const int* __restrict__ counts,
    const int* __restrict__ t2e, const int* __restrict__ t2pos,
    const float* __restrict__ t2p, float* __restrict__ out) {
  int t = blockIdx.x;
  int e0 = t2e[2 * t], e1 = t2e[2 * t + 1];
  int b = 0, b0 = 0, b1 = 0;
  #pragma unroll
  for (int ee = 0; ee < E; ++ee) {
    if (ee == e0) b0 = b;
    if (ee == e1) b1 = b;
    int c = counts[ee * CSTR];
    b += (c + TM - 1) / TM * TM;
  }
  int r0 = b0 + t2pos[2 * t];
  int r1 = b1 + t2pos[2 * t + 1];
  float p0 = t2p[2 * t], p1 = t2p[2 * t + 1];
  int d = threadIdx.x * 4;
  half4 h0 = *(const half4*)(Yp + (size_t)r0 * D + d);
  half4 h1 = *(const half4*)(Yp + (size_t)r1 * D + d);
  float4 o;
  o.x = p0 * (float)h0.x + p1 * (float)h1.x;
  o.y = p0 * (float)h0.y + p1 * (float)h1.y;
  o.z = p0 * (float)h0.z + p1 * (float)h1.z;
  o.w = p0 * (float)h0.w + p1 * (float)h1.w;
  *(float4*)(out + (size_t)t * D + d) = o;
}

// ---------------- launch ----------------
extern "C" void kernel_launch(void* const* d_in, const int* in_sizes, int n_in,
                              void* d_out, int out_size, void* d_ws, size_t ws_size,
                              hipStream_t stream) {
  const float* x     = (const float*)d_in[0];
  const float* wgate = (const float*)d_in[1];
  const float* w_g   = (const float*)d_in[2];
  const float* w_u   = (const float*)d_in[3];
  const float* w_d   = (const float*)d_in[4];
  float* out = (float*)d_out;
  char* ws = (char*)d_ws;

  if (ws_size < WS_NEED) {
    fprintf(stderr, "kernel_launch: ws_size=%zu < needed %zu\n", ws_size, WS_NEED);
    return;
  }

  int* counts   = (int*)(ws + OFF_COUNTS);
  int* tlist    = (int*)(ws + OFF_TLIST);
  int* t2e      = (int*)(ws + OFF_T2E);
  int* t2pos    = (int*)(ws + OFF_T2POS);
  float* t2p    = (float*)(ws + OFF_T2P);
  _Float16* Xh  = (_Float16*)(ws + OFF_XG);   // rows 0..T-1; region reused as Yp
  _Float16* Hid = (_Float16*)(ws + OFF_HID);
  _Float16* wgT = (_Float16*)(ws + OFF_WGT);
  _Float16* wuT = (_Float16*)(ws + OFF_WUT);
  _Float16* wdT = (_Float16*)(ws + OFF_WDT);

  hipMemsetAsync(counts, 0, (size_t)E * CSTR * 4, stream);

  k_prep<<<PREP_GRID, 256, 0, stream>>>(x, wgate, w_g, w_u, Xh,
                                        wgT, wuT, counts, tlist,
                                        t2e, t2pos, t2p);
  k_upgate<<<UPG_GRID, 256, 0, stream>>>(Xh, wgT, wuT, Hid, counts, tlist,
                                         w_d, wdT);
  _Float16* Yp = Xh;   // Xh dead after upgate; reuse region as Yp
  k_down<<<E * MT_MAX * NT_DN, 256, 0, stream>>>(Hid, wdT, Yp, counts);
  k_combine<<<T, 256, 0, stream>>>(Yp, counts, t2e, t2pos, t2p, out);
}